// Round 8
// baseline (916.396 us; speedup 1.0000x reference)
//
#include <hip/hip_runtime.h>
#include <hip/hip_fp16.h>

// SheafConvLayer on MI355X — R7: no CSR sort; bucket-grouped records consumed
// by an LDS-accumulating gather. binplace writes are LDS-staged + coalesced.
// 5 kernels: A=(node_pre || hist) -> colscan -> binplace -> diag -> gather.

#define NBLK_BIN 256     // blocks for hist/binplace edge chunking
#define CHUNK_CAP 4096   // max pairs per binplace block (staged path)
#define STAGE_CAP 8192   // max directed entries per binplace block

// ---------------------------------------------------------------- kernel A
__global__ __launch_bounds__(256) void k_pre_hist(
    const float* __restrict__ x,
    const float* __restrict__ Wsheaf,  // 128
    const float* __restrict__ Wlin,    // 64x64 row-major, y = x @ Wlin^T
    const float* __restrict__ blin,    // 64
    float2* __restrict__ s12,
    __half* __restrict__ yz,           // y (fp16); later scaled to z in place
    const int* __restrict__ row, const int* __restrict__ col,
    unsigned* __restrict__ table,
    int N, int Eh, int NB, int NPRE)
{
    __shared__ float4 xt[64 * 16];     // 16 KB; hist path aliases it
    int tid = threadIdx.x;

    if (blockIdx.x >= NPRE) {
        unsigned* h = (unsigned*)xt;
        int hb = blockIdx.x - NPRE;
        for (int i = tid; i < NB; i += 256) h[i] = 0;
        __syncthreads();
        int chunk = (Eh + NBLK_BIN - 1) / NBLK_BIN;
        int lo = hb * chunk, hi = min(lo + chunk, Eh);
        for (int i = lo + tid; i < hi; i += 256) {
            atomicAdd(&h[(unsigned)row[i] >> 8], 1u);
            atomicAdd(&h[(unsigned)col[i] >> 8], 1u);
        }
        __syncthreads();
        for (int i = tid; i < NB; i += 256) table[(size_t)hb * NB + i] = h[i];
        return;
    }

    int lane = tid & 63;
    int wave = tid >> 6;
    int n0   = blockIdx.x * 64;

    float wreg[64];
    {
        const float4* Wv = (const float4*)(Wlin + lane * 64);
        #pragma unroll
        for (int q = 0; q < 16; ++q) {
            float4 w4 = Wv[q];
            wreg[4 * q + 0] = w4.x; wreg[4 * q + 1] = w4.y;
            wreg[4 * q + 2] = w4.z; wreg[4 * q + 3] = w4.w;
        }
    }
    float bl  = blin[lane];
    float ws1 = Wsheaf[lane];
    float ws2 = Wsheaf[64 + lane];

    int nvalid = min(64, N - n0);
    const float4* xg = (const float4*)(x + (size_t)n0 * 64);
    for (int i = tid; i < nvalid * 16; i += 256) xt[i] = xg[i];
    __syncthreads();

    int ni_end = min(wave * 16 + 16, nvalid);
    for (int ni = wave * 16; ni < ni_end; ++ni) {
        float xv = ((const float*)xt)[ni * 64 + lane];
        float a = xv * ws1, b = xv * ws2;
        #pragma unroll
        for (int m = 32; m; m >>= 1) {
            a += __shfl_xor(a, m);
            b += __shfl_xor(b, m);
        }
        if (lane == 0) s12[n0 + ni] = make_float2(a, b);

        float acc = bl;
        #pragma unroll
        for (int q = 0; q < 16; ++q) {
            float4 xq = xt[ni * 16 + q];
            acc += xq.x * wreg[4 * q + 0] + xq.y * wreg[4 * q + 1]
                 + xq.z * wreg[4 * q + 2] + xq.w * wreg[4 * q + 3];
        }
        yz[(size_t)(n0 + ni) * 64 + lane] = __float2half(acc);
    }
}

// ------------------------------------------------------------- colscan
__global__ __launch_bounds__(256) void k_colscan(
    unsigned* __restrict__ table, unsigned* __restrict__ colsum, int NB)
{
    __shared__ unsigned sm[256];
    int j = blockIdx.x, t = threadIdx.x;
    unsigned v = table[(size_t)t * NB + j];
    sm[t] = v;
    __syncthreads();
    for (int off = 1; off < 256; off <<= 1) {
        unsigned u = (t >= off) ? sm[t - off] : 0;
        __syncthreads();
        if (t >= off) sm[t] += u;
        __syncthreads();
    }
    table[(size_t)t * NB + j] = sm[t] - v;   // exclusive over blocks
    if (t == 255) colsum[j] = sm[255];
}

// ------------------------------------------------------------- binplace
// Stages entries bucket-sorted in LDS, then writes contiguous runs.
// Entry: { key = rowlocal<<17 | other , half2(m^2, prod) }
__global__ __launch_bounds__(512, 1) void k_binplace(
    const float2* __restrict__ s12,
    const int* __restrict__ row, const int* __restrict__ col,
    const unsigned* __restrict__ table, const unsigned* __restrict__ colsum,
    uint2* __restrict__ binned, int Eh, int NB)
{
    __shared__ unsigned csum[512];
    __shared__ unsigned destbase[512];
    __shared__ unsigned h[512];
    __shared__ unsigned locex[512];
    __shared__ unsigned cur[512];
    __shared__ uint2    stg[STAGE_CAP];     // 64 KB
    __shared__ unsigned gaddr[STAGE_CAP];   // 32 KB
    __shared__ __half2  pm[CHUNK_CAP];      // 16 KB

    int t = threadIdx.x;

    // ebase (exclusive scan of colsum) + this block's reserved offsets
    unsigned v = (t < NB) ? colsum[t] : 0;
    csum[t] = v;
    __syncthreads();
    for (int off = 1; off < 512; off <<= 1) {
        unsigned u = (t >= off) ? csum[t - off] : 0;
        __syncthreads();
        csum[t] += u;
        __syncthreads();
    }
    if (t < NB) destbase[t] = (csum[t] - v) + table[(size_t)blockIdx.x * NB + t];
    h[t] = 0;
    cur[t] = 0;
    __syncthreads();

    int chunk = (Eh + NBLK_BIN - 1) / NBLK_BIN;
    int lo = blockIdx.x * chunk, hi = min(lo + chunk, Eh);

    if (chunk <= CHUNK_CAP) {
        // ---- pass A: tanh once, local histogram
        for (int i = lo + t; i < hi; i += 512) {
            int r = row[i], c = col[i];
            float2 sr = s12[r], sc2 = s12[c];
            float mf = tanhf(sr.x + sc2.y);
            float mr = tanhf(sc2.x + sr.y);
            pm[i - lo] = __halves2half2(__float2half_rn(mf), __float2half_rn(mr));
            atomicAdd(&h[(unsigned)r >> 8], 1u);
            atomicAdd(&h[(unsigned)c >> 8], 1u);
        }
        __syncthreads();
        // ---- scan h -> locex
        unsigned hv = h[t];
        csum[t] = hv;
        __syncthreads();
        for (int off = 1; off < 512; off <<= 1) {
            unsigned u = (t >= off) ? csum[t - off] : 0;
            __syncthreads();
            csum[t] += u;
            __syncthreads();
        }
        locex[t] = csum[t] - hv;
        __syncthreads();
        // ---- pass B: place into LDS, record global dst
        for (int i = lo + t; i < hi; i += 512) {
            int r = row[i], c = col[i];
            __half2 m = pm[i - lo];
            float mf = __low2float(m), mr = __high2float(m);
            float pr = mf * mr;

            unsigned bk_r = (unsigned)r >> 8;
            unsigned pos1 = atomicAdd(&cur[bk_r], 1u);
            unsigned s1i  = locex[bk_r] + pos1;
            __half2 h1 = __halves2half2(__float2half_rn(mf * mf), __float2half_rn(pr));
            stg[s1i]   = make_uint2(((unsigned)(r & 255) << 17) | (unsigned)c,
                                    *reinterpret_cast<unsigned*>(&h1));
            gaddr[s1i] = destbase[bk_r] + pos1;

            unsigned bk_c = (unsigned)c >> 8;
            unsigned pos2 = atomicAdd(&cur[bk_c], 1u);
            unsigned s2i  = locex[bk_c] + pos2;
            __half2 h2 = __halves2half2(__float2half_rn(mr * mr), __float2half_rn(pr));
            stg[s2i]   = make_uint2(((unsigned)(c & 255) << 17) | (unsigned)r,
                                    *reinterpret_cast<unsigned*>(&h2));
            gaddr[s2i] = destbase[bk_c] + pos2;
        }
        __syncthreads();
        // ---- pass C: coalesced run writes
        int total = (hi > lo) ? 2 * (hi - lo) : 0;
        for (int i = t; i < total; i += 512) binned[gaddr[i]] = stg[i];
    } else {
        // fallback: direct scattered stores (correct for any size)
        for (int i = lo + t; i < hi; i += 512) {
            int r = row[i], c = col[i];
            float2 sr = s12[r], sc2 = s12[c];
            float mf = tanhf(sr.x + sc2.y);
            float mr = tanhf(sc2.x + sr.y);
            float pr = mf * mr;
            __half2 h1 = __halves2half2(__float2half_rn(mf * mf), __float2half_rn(pr));
            unsigned bk_r = (unsigned)r >> 8;
            unsigned d1 = destbase[bk_r] + atomicAdd(&cur[bk_r], 1u);
            binned[d1] = make_uint2(((unsigned)(r & 255) << 17) | (unsigned)c,
                                    *reinterpret_cast<unsigned*>(&h1));
            __half2 h2 = __halves2half2(__float2half_rn(mr * mr), __float2half_rn(pr));
            unsigned bk_c = (unsigned)c >> 8;
            unsigned d2 = destbase[bk_c] + atomicAdd(&cur[bk_c], 1u);
            binned[d2] = make_uint2(((unsigned)(c & 255) << 17) | (unsigned)r,
                                    *reinterpret_cast<unsigned*>(&h2));
        }
    }
}

// ----------------------------------------------------------------- diag
// Per bucket: dsum via LDS float atomics -> dinv; z := dinv*y in place.
__global__ __launch_bounds__(256) void k_diag(
    const uint2* __restrict__ binned,
    const unsigned* __restrict__ colsum,
    float* __restrict__ dinv,
    __half* __restrict__ yz,
    int N, int NB)
{
    __shared__ float dsum[256];
    __shared__ unsigned red[256];
    __shared__ float sdv[256];

    int b = blockIdx.x, t = threadIdx.x;
    int row0 = b << 8;

    unsigned part = 0;
    for (int j = t; j < b; j += 256) part += colsum[j];
    red[t] = part;
    dsum[t] = 0.0f;
    __syncthreads();
    for (int m = 128; m; m >>= 1) {
        if (t < m) red[t] += red[t + m];
        __syncthreads();
    }
    int lo = (int)red[0];
    int hi = lo + (int)colsum[b];

    for (int i = lo + t; i < hi; i += 256) {
        uint2 v = binned[i];
        __half2 h = *reinterpret_cast<__half2*>(&v.y);
        atomicAdd(&dsum[v.x >> 17], __low2float(h));   // m^2
    }
    __syncthreads();

    float dv = rsqrtf(dsum[t] + 1.0f);
    sdv[t] = dv;
    int rn = row0 + t;
    if (rn < N) dinv[rn] = dv;
    __syncthreads();

    // z := dinv * y (half2-vectorized, coalesced)
    __half2* yz2 = (__half2*)yz;
    for (int i = t; i < 256 * 32; i += 256) {
        int rl = i >> 5;
        int rn2 = row0 + rl;
        if (rn2 < N) {
            size_t idx = (size_t)rn2 * 32 + (i & 31);
            __half2 v = yz2[idx];
            float s = sdv[rl];
            yz2[idx] = __floats2half2_rn(s * __low2float(v), s * __high2float(v));
        }
    }
}

// --------------------------------------------------------------- gather
// One block per bucket: acc[256][64] f32 in LDS; stream bucket entries,
// ds_add accumulate, fused epilogue.
__global__ __launch_bounds__(512, 2) void k_gather(
    const float* __restrict__ x,
    const __half* __restrict__ zh,
    const float* __restrict__ dinv,
    const uint2* __restrict__ binned,
    const unsigned* __restrict__ colsum,
    float* __restrict__ out,
    int N, int NB)
{
    __shared__ float acc[256 * 64];    // 64 KB
    __shared__ unsigned red[512];

    int t = threadIdx.x, b = blockIdx.x;
    int row0 = b << 8;
    int lane = t & 63, wave = t >> 6;  // 8 waves

    unsigned part = 0;
    for (int j = t; j < b; j += 512) part += colsum[j];
    red[t] = part;
    __syncthreads();
    for (int m = 256; m; m >>= 1) {
        if (t < m) red[t] += red[t + m];
        __syncthreads();
    }
    int lo = (int)red[0];
    int hi = lo + (int)colsum[b];

    for (int i = t; i < 256 * 64; i += 512) acc[i] = 0.0f;
    __syncthreads();

    for (int b64 = lo + wave * 64; b64 < hi; b64 += 8 * 64) {
        int m = min(64, hi - b64);
        uint2 rec = (lane < m) ? binned[b64 + lane] : make_uint2(0u, 0u);
        if (m == 64) {
            #pragma unroll 4
            for (int j = 0; j < 64; ++j) {
                unsigned kx = __shfl(rec.x, j);
                unsigned ky = __shfl(rec.y, j);
                unsigned rl = kx >> 17, other = kx & 0x1FFFFu;
                __half2 h = *reinterpret_cast<__half2*>(&ky);
                float pr = __high2float(h);
                float zv = __half2float(zh[(size_t)other * 64 + lane]);
                atomicAdd(&acc[(rl << 6) | lane], pr * zv);
            }
        } else {
            for (int j = 0; j < m; ++j) {
                unsigned kx = __shfl(rec.x, j);
                unsigned ky = __shfl(rec.y, j);
                unsigned rl = kx >> 17, other = kx & 0x1FFFFu;
                __half2 h = *reinterpret_cast<__half2*>(&ky);
                float pr = __high2float(h);
                float zv = __half2float(zh[(size_t)other * 64 + lane]);
                atomicAdd(&acc[(rl << 6) | lane], pr * zv);
            }
        }
    }
    __syncthreads();

    // epilogue: out = x - (1/dv - dv)*z + dv*acc   (y = z/dv)
    for (int i = t; i < 256 * 64; i += 512) {
        int rl = i >> 6, ln = i & 63;
        int rn = row0 + rl;
        if (rn < N) {
            float dv = dinv[rn];
            size_t idx = (size_t)rn * 64 + ln;
            float zv = __half2float(zh[idx]);
            out[idx] = x[idx] - (1.0f / dv - dv) * zv + dv * acc[i];
        }
    }
}

extern "C" void kernel_launch(void* const* d_in, const int* in_sizes, int n_in,
                              void* d_out, int out_size, void* d_ws, size_t ws_size,
                              hipStream_t stream) {
    const float* x      = (const float*)d_in[0];
    const float* Wsheaf = (const float*)d_in[1];
    const float* Wlin   = (const float*)d_in[2];
    const float* blin   = (const float*)d_in[3];
    const int*   ei     = (const int*)d_in[4];
    float* out = (float*)d_out;

    int N  = in_sizes[0] / 64;
    int E  = in_sizes[4] / 2;      // total directed edges/entries
    int Eh = E >> 1;               // node pairs
    int NB = (N + 255) >> 8;       // buckets of 256 rows (<=512 supported)
    int NPRE = (N + 63) / 64;
    const int* row = ei;           // edge_index[0]; first Eh = src
    const int* col = ei + E;       // edge_index[1]; first Eh = dst

    char* ws = (char*)d_ws;
    float2*   s12    = (float2*)ws;             ws += (size_t)N * 8;
    uint2*    binned = (uint2*)ws;              ws += (size_t)E * 8;
    unsigned* table  = (unsigned*)ws;           ws += (size_t)NBLK_BIN * NB * 4;
    unsigned* colsum = (unsigned*)ws;           ws += (size_t)NB * 4;
    float*    dinv   = (float*)ws;              ws += (size_t)N * 4;
    __half*   yz     = (__half*)ws;             ws += (size_t)N * 64 * 2;

    k_pre_hist <<<NPRE + NBLK_BIN, 256, 0, stream>>>(x, Wsheaf, Wlin, blin, s12, yz,
                                                     row, col, table, N, Eh, NB, NPRE);
    k_colscan  <<<NB, 256, 0, stream>>>(table, colsum, NB);
    k_binplace <<<NBLK_BIN, 512, 0, stream>>>(s12, row, col, table, colsum, binned, Eh, NB);
    k_diag     <<<NB, 256, 0, stream>>>(binned, colsum, dinv, yz, N, NB);
    k_gather   <<<NB, 512, 0, stream>>>(x, yz, dinv, binned, colsum, out, N, NB);
}

// Round 9
// 246.750 us; speedup vs baseline: 3.7139x; 3.7139x over previous
//
#include <hip/hip_runtime.h>
#include <hip/hip_fp16.h>

// SheafConvLayer on MI355X — R8 = R6 structure (proven 257us) with R7's
// LDS-staged coalesced-write binplace. 5 kernels:
// A=(node_pre || hist) -> colscan -> binplace(staged) -> bucket -> gather.

#define NBLK_BIN 256     // blocks for hist/binplace edge chunking
#define CHUNK_CAP 4096   // max pairs per binplace block (staged path)
#define STAGE_CAP 8192   // max directed entries per binplace block

// ---------------------------------------------------------------- kernel A
__global__ __launch_bounds__(256) void k_pre_hist(
    const float* __restrict__ x,
    const float* __restrict__ Wsheaf,  // 128
    const float* __restrict__ Wlin,    // 64x64 row-major, y = x @ Wlin^T
    const float* __restrict__ blin,    // 64
    float2* __restrict__ s12,
    __half* __restrict__ yz,           // y (fp16); later scaled to z in place
    const int* __restrict__ row, const int* __restrict__ col,
    unsigned* __restrict__ table,
    int N, int Eh, int NB, int NPRE)
{
    __shared__ float4 xt[64 * 16];     // 16 KB; hist path aliases it
    int tid = threadIdx.x;

    if (blockIdx.x >= NPRE) {
        unsigned* h = (unsigned*)xt;
        int hb = blockIdx.x - NPRE;
        for (int i = tid; i < NB; i += 256) h[i] = 0;
        __syncthreads();
        int chunk = (Eh + NBLK_BIN - 1) / NBLK_BIN;
        int lo = hb * chunk, hi = min(lo + chunk, Eh);
        for (int i = lo + tid; i < hi; i += 256) {
            atomicAdd(&h[(unsigned)row[i] >> 8], 1u);
            atomicAdd(&h[(unsigned)col[i] >> 8], 1u);
        }
        __syncthreads();
        for (int i = tid; i < NB; i += 256) table[(size_t)hb * NB + i] = h[i];
        return;
    }

    int lane = tid & 63;
    int wave = tid >> 6;
    int n0   = blockIdx.x * 64;

    float wreg[64];
    {
        const float4* Wv = (const float4*)(Wlin + lane * 64);
        #pragma unroll
        for (int q = 0; q < 16; ++q) {
            float4 w4 = Wv[q];
            wreg[4 * q + 0] = w4.x; wreg[4 * q + 1] = w4.y;
            wreg[4 * q + 2] = w4.z; wreg[4 * q + 3] = w4.w;
        }
    }
    float bl  = blin[lane];
    float ws1 = Wsheaf[lane];
    float ws2 = Wsheaf[64 + lane];

    int nvalid = min(64, N - n0);
    const float4* xg = (const float4*)(x + (size_t)n0 * 64);
    for (int i = tid; i < nvalid * 16; i += 256) xt[i] = xg[i];
    __syncthreads();

    int ni_end = min(wave * 16 + 16, nvalid);
    for (int ni = wave * 16; ni < ni_end; ++ni) {
        float xv = ((const float*)xt)[ni * 64 + lane];
        float a = xv * ws1, b = xv * ws2;
        #pragma unroll
        for (int m = 32; m; m >>= 1) {
            a += __shfl_xor(a, m);
            b += __shfl_xor(b, m);
        }
        if (lane == 0) s12[n0 + ni] = make_float2(a, b);

        float acc = bl;
        #pragma unroll
        for (int q = 0; q < 16; ++q) {
            float4 xq = xt[ni * 16 + q];
            acc += xq.x * wreg[4 * q + 0] + xq.y * wreg[4 * q + 1]
                 + xq.z * wreg[4 * q + 2] + xq.w * wreg[4 * q + 3];
        }
        yz[(size_t)(n0 + ni) * 64 + lane] = __float2half(acc);
    }
}

// ------------------------------------------------------------- colscan
__global__ __launch_bounds__(256) void k_colscan(
    unsigned* __restrict__ table, unsigned* __restrict__ colsum, int NB)
{
    __shared__ unsigned sm[256];
    int j = blockIdx.x, t = threadIdx.x;
    unsigned v = table[(size_t)t * NB + j];
    sm[t] = v;
    __syncthreads();
    for (int off = 1; off < 256; off <<= 1) {
        unsigned u = (t >= off) ? sm[t - off] : 0;
        __syncthreads();
        if (t >= off) sm[t] += u;
        __syncthreads();
    }
    table[(size_t)t * NB + j] = sm[t] - v;   // exclusive over blocks
    if (t == 255) colsum[j] = sm[255];
}

// ------------------------------------------------------------- binplace
// Stages entries bucket-sorted in LDS, then writes contiguous runs.
// Entry: { key = rowlocal<<17 | other , half2(m^2, prod) }
__global__ __launch_bounds__(512, 1) void k_binplace(
    const float2* __restrict__ s12,
    const int* __restrict__ row, const int* __restrict__ col,
    const unsigned* __restrict__ table, const unsigned* __restrict__ colsum,
    uint2* __restrict__ binned, int Eh, int NB)
{
    __shared__ unsigned csum[512];
    __shared__ unsigned destbase[512];
    __shared__ unsigned h[512];
    __shared__ unsigned locex[512];
    __shared__ unsigned cur[512];
    __shared__ uint2    stg[STAGE_CAP];     // 64 KB
    __shared__ unsigned gaddr[STAGE_CAP];   // 32 KB
    __shared__ __half2  pm[CHUNK_CAP];      // 16 KB

    int t = threadIdx.x;

    // ebase (exclusive scan of colsum) + this block's reserved offsets
    unsigned v = (t < NB) ? colsum[t] : 0;
    csum[t] = v;
    __syncthreads();
    for (int off = 1; off < 512; off <<= 1) {
        unsigned u = (t >= off) ? csum[t - off] : 0;
        __syncthreads();
        csum[t] += u;
        __syncthreads();
    }
    if (t < NB) destbase[t] = (csum[t] - v) + table[(size_t)blockIdx.x * NB + t];
    h[t] = 0;
    cur[t] = 0;
    __syncthreads();

    int chunk = (Eh + NBLK_BIN - 1) / NBLK_BIN;
    int lo = blockIdx.x * chunk, hi = min(lo + chunk, Eh);

    if (chunk <= CHUNK_CAP) {
        // ---- pass A: tanh once, local histogram
        for (int i = lo + t; i < hi; i += 512) {
            int r = row[i], c = col[i];
            float2 sr = s12[r], sc2 = s12[c];
            float mf = tanhf(sr.x + sc2.y);
            float mr = tanhf(sc2.x + sr.y);
            pm[i - lo] = __halves2half2(__float2half_rn(mf), __float2half_rn(mr));
            atomicAdd(&h[(unsigned)r >> 8], 1u);
            atomicAdd(&h[(unsigned)c >> 8], 1u);
        }
        __syncthreads();
        // ---- scan h -> locex
        unsigned hv = h[t];
        csum[t] = hv;
        __syncthreads();
        for (int off = 1; off < 512; off <<= 1) {
            unsigned u = (t >= off) ? csum[t - off] : 0;
            __syncthreads();
            csum[t] += u;
            __syncthreads();
        }
        locex[t] = csum[t] - hv;
        __syncthreads();
        // ---- pass B: place into LDS, record global dst
        for (int i = lo + t; i < hi; i += 512) {
            int r = row[i], c = col[i];
            __half2 m = pm[i - lo];
            float mf = __low2float(m), mr = __high2float(m);
            float pr = mf * mr;

            unsigned bk_r = (unsigned)r >> 8;
            unsigned pos1 = atomicAdd(&cur[bk_r], 1u);
            unsigned s1i  = locex[bk_r] + pos1;
            __half2 h1 = __halves2half2(__float2half_rn(mf * mf), __float2half_rn(pr));
            stg[s1i]   = make_uint2(((unsigned)(r & 255) << 17) | (unsigned)c,
                                    *reinterpret_cast<unsigned*>(&h1));
            gaddr[s1i] = destbase[bk_r] + pos1;

            unsigned bk_c = (unsigned)c >> 8;
            unsigned pos2 = atomicAdd(&cur[bk_c], 1u);
            unsigned s2i  = locex[bk_c] + pos2;
            __half2 h2 = __halves2half2(__float2half_rn(mr * mr), __float2half_rn(pr));
            stg[s2i]   = make_uint2(((unsigned)(c & 255) << 17) | (unsigned)r,
                                    *reinterpret_cast<unsigned*>(&h2));
            gaddr[s2i] = destbase[bk_c] + pos2;
        }
        __syncthreads();
        // ---- pass C: coalesced run writes
        int total = (hi > lo) ? 2 * (hi - lo) : 0;
        for (int i = t; i < total; i += 512) binned[gaddr[i]] = stg[i];
    } else {
        // fallback: direct scattered stores (correct for any size)
        for (int i = lo + t; i < hi; i += 512) {
            int r = row[i], c = col[i];
            float2 sr = s12[r], sc2 = s12[c];
            float mf = tanhf(sr.x + sc2.y);
            float mr = tanhf(sc2.x + sr.y);
            float pr = mf * mr;
            __half2 h1 = __halves2half2(__float2half_rn(mf * mf), __float2half_rn(pr));
            unsigned bk_r = (unsigned)r >> 8;
            unsigned d1 = destbase[bk_r] + atomicAdd(&cur[bk_r], 1u);
            binned[d1] = make_uint2(((unsigned)(r & 255) << 17) | (unsigned)c,
                                    *reinterpret_cast<unsigned*>(&h1));
            __half2 h2 = __halves2half2(__float2half_rn(mr * mr), __float2half_rn(pr));
            unsigned bk_c = (unsigned)c >> 8;
            unsigned d2 = destbase[bk_c] + atomicAdd(&cur[bk_c], 1u);
            binned[d2] = make_uint2(((unsigned)(c & 255) << 17) | (unsigned)r,
                                    *reinterpret_cast<unsigned*>(&h2));
        }
    }
}

// --------------------------------------------------------------- bucket
// One block per bucket: count + diag via LDS, scan -> base/dinv, place
// row-sorted records into sc, then z := dinv*y in place for own rows.
__global__ __launch_bounds__(256) void k_bucket(
    const uint2* __restrict__ binned,
    const unsigned* __restrict__ colsum,
    int* __restrict__ base, float* __restrict__ dinv,
    int2* __restrict__ sc,
    __half* __restrict__ yz,
    int N, int NB)
{
    __shared__ unsigned cnt[256];
    __shared__ float dsum[256];
    __shared__ unsigned pref[256];
    __shared__ unsigned cur[256];
    __shared__ float sdinv[256];
    __shared__ unsigned red[256];

    int b = blockIdx.x, t = threadIdx.x;
    int row0 = b << 8;

    // lo = sum(colsum[0..b)), hi = lo + colsum[b]
    unsigned part = 0;
    for (int j = t; j < b; j += 256) part += colsum[j];
    red[t] = part;
    cnt[t] = 0;
    dsum[t] = 0.0f;
    __syncthreads();
    for (int m = 128; m; m >>= 1) {
        if (t < m) red[t] += red[t + m];
        __syncthreads();
    }
    int lo = (int)red[0];
    int hi = lo + (int)colsum[b];

    for (int i = lo + t; i < hi; i += 256) {
        uint2 v = binned[i];
        unsigned rl = v.x >> 17;
        atomicAdd(&cnt[rl], 1u);
        __half2 h = *reinterpret_cast<__half2*>(&v.y);
        atomicAdd(&dsum[rl], __low2float(h));      // m^2
    }
    __syncthreads();

    unsigned myc = cnt[t];
    pref[t] = myc;
    __syncthreads();
    for (int off = 1; off < 256; off <<= 1) {
        unsigned u = (t >= off) ? pref[t - off] : 0;
        __syncthreads();
        if (t >= off) pref[t] += u;
        __syncthreads();
    }
    unsigned excl = pref[t] - myc;
    float dv = rsqrtf(dsum[t] + 1.0f);
    sdinv[t] = dv;
    int rown = row0 + t;
    if (rown < N) {
        base[rown] = lo + (int)excl;
        dinv[rown] = dv;
    }
    if (b == (int)gridDim.x - 1 && t == 0) base[N] = hi;
    cur[t] = excl;
    __syncthreads();

    for (int i = lo + t; i < hi; i += 256) {
        uint2 v = binned[i];
        unsigned rl = v.x >> 17;
        unsigned other = v.x & 0x1FFFFu;
        unsigned slot = (unsigned)lo + atomicAdd(&cur[rl], 1u);
        __half2 h = *reinterpret_cast<__half2*>(&v.y);
        sc[slot] = make_int2((int)other, __float_as_int(__high2float(h)));
    }

    // z := dinv * y in place for this bucket's rows (half2-vectorized)
    __half2* yz2 = (__half2*)yz;
    for (int i = t; i < 256 * 32; i += 256) {
        int rl = i >> 5;
        int rn = row0 + rl;
        if (rn < N) {
            size_t idx = (size_t)rn * 32 + (i & 31);
            __half2 v = yz2[idx];
            float s = sdinv[rl];
            yz2[idx] = __floats2half2_rn(s * __low2float(v), s * __high2float(v));
        }
    }
}

// --------------------------------------------------------------- gather
__global__ __launch_bounds__(256) void k_node_gather(
    const float* __restrict__ x,
    const __half* __restrict__ zh,
    const float* __restrict__ dinv,
    const int* __restrict__ base,
    const int2* __restrict__ sc,
    float* __restrict__ out,
    int N)
{
    __shared__ int2 stage[4][64];
    int lane = threadIdx.x & 63;
    int wave = threadIdx.x >> 6;
    int n = blockIdx.x * 4 + wave;
    if (n >= N) return;

    int j0 = base[n], end = base[n + 1];
    float acc = 0.0f;
    for (int blk = j0; blk < end; blk += 64) {
        int m = min(64, end - blk);
        if (lane < m) stage[wave][lane] = sc[blk + lane];   // coalesced
        #pragma unroll 4
        for (int j = 0; j < m; ++j) {
            int2 r = stage[wave][j];                         // LDS broadcast
            acc += __int_as_float(r.y) * __half2float(zh[(size_t)r.x * 64 + lane]);
        }
    }
    float dv = dinv[n];
    int idx = n * 64 + lane;
    float zv = __half2float(zh[idx]);
    // out = x - (1-dv^2)*y + dv*acc, with y = z/dv  =>  (1/dv - dv)*z
    out[idx] = x[idx] - (1.0f / dv - dv) * zv + dv * acc;
}

extern "C" void kernel_launch(void* const* d_in, const int* in_sizes, int n_in,
                              void* d_out, int out_size, void* d_ws, size_t ws_size,
                              hipStream_t stream) {
    const float* x      = (const float*)d_in[0];
    const float* Wsheaf = (const float*)d_in[1];
    const float* Wlin   = (const float*)d_in[2];
    const float* blin   = (const float*)d_in[3];
    const int*   ei     = (const int*)d_in[4];
    float* out = (float*)d_out;

    int N  = in_sizes[0] / 64;
    int E  = in_sizes[4] / 2;      // total directed edges/entries
    int Eh = E >> 1;               // node pairs
    int NB = (N + 255) >> 8;       // buckets of 256 rows (<=512 supported)
    int NPRE = (N + 63) / 64;
    const int* row = ei;           // edge_index[0]; first Eh = src
    const int* col = ei + E;       // edge_index[1]; first Eh = dst

    char* ws = (char*)d_ws;
    float2*   s12    = (float2*)ws;             ws += (size_t)N * 8;
    uint2*    binned = (uint2*)ws;              ws += (size_t)E * 8;
    int2*     sc     = (int2*)ws;               ws += (size_t)E * 8;
    unsigned* table  = (unsigned*)ws;           ws += (size_t)NBLK_BIN * NB * 4;
    unsigned* colsum = (unsigned*)ws;           ws += (size_t)NB * 4;
    int*      base   = (int*)ws;                ws += (size_t)(N + 1) * 4;
    float*    dinv   = (float*)ws;              ws += (size_t)N * 4;
    __half*   yz     = (__half*)ws;             ws += (size_t)N * 64 * 2;

    k_pre_hist <<<NPRE + NBLK_BIN, 256, 0, stream>>>(x, Wsheaf, Wlin, blin, s12, yz,
                                                     row, col, table, N, Eh, NB, NPRE);
    k_colscan  <<<NB, 256, 0, stream>>>(table, colsum, NB);
    k_binplace <<<NBLK_BIN, 512, 0, stream>>>(s12, row, col, table, colsum, binned, Eh, NB);
    k_bucket   <<<NB, 256, 0, stream>>>(binned, colsum, base, dinv, sc, yz, N, NB);
    k_node_gather<<<(N + 3) / 4, 256, 0, stream>>>(x, yz, dinv, base, sc, out, N);
}